// Round 1
// baseline (363.406 us; speedup 1.0000x reference)
//
#include <hip/hip_runtime.h>

// Problem: B=16 batches, N=500000 events each, event = (t, x, y, p) float32.
// Output: (B, 720, 1280, 3) float32. Per pixel, LAST event (highest index i
// within the batch) that lands on it decides:
//   p==1 -> (0, 255, 255);  p==0 -> (255, 0, 255);  untouched -> (255, 255, 510)
// Last-wins is reproduced exactly via atomicMax over key = ((i+1)<<1)|p.

#define WIDTH  1280
#define HEIGHT 720
#define BATCH  16
#define NEV    500000
#define NPIX   (BATCH * HEIGHT * WIDTH)   // 14,745,600 (divisible by 4)

__global__ __launch_bounds__(256) void e2img_events(const float4* __restrict__ ev,
                                                    unsigned int* __restrict__ win) {
    int idx = blockIdx.x * 256 + threadIdx.x;
    if (idx >= BATCH * NEV) return;
    float4 e = ev[idx];                       // (t, x, y, p), 16B coalesced
    int b  = idx / NEV;
    int i  = idx - b * NEV;                   // event index within batch
    int xi = (int)floorf(e.y);
    int yi = (int)floorf(e.z);
    unsigned int pbit = (e.w == 1.0f) ? 1u : 0u;
    unsigned int key  = ((unsigned int)(i + 1) << 1) | pbit;   // >0 => touched
    atomicMax(&win[(size_t)b * (HEIGHT * WIDTH) + yi * WIDTH + xi], key);
}

__global__ __launch_bounds__(256) void e2img_decode(const uint4* __restrict__ win4,
                                                    float4* __restrict__ out4) {
    int t = blockIdx.x * 256 + threadIdx.x;
    if (t >= NPIX / 4) return;
    uint4 w = win4[t];
    unsigned int ks[4] = {w.x, w.y, w.z, w.w};
    float v[12];
#pragma unroll
    for (int j = 0; j < 4; ++j) {
        unsigned int k = ks[j];
        float y0, y1, y2;
        if (k == 0u) { y0 = 255.0f; y1 = 255.0f; y2 = 510.0f; }
        else {
            int p = (int)(k & 1u);
            y0 = p ? 0.0f : 255.0f;
            y1 = p ? 255.0f : 0.0f;
            y2 = 255.0f;
        }
        v[3 * j + 0] = y0;
        v[3 * j + 1] = y1;
        v[3 * j + 2] = y2;
    }
    float4* o = out4 + (size_t)3 * t;         // 48B contiguous per thread
    o[0] = make_float4(v[0], v[1], v[2], v[3]);
    o[1] = make_float4(v[4], v[5], v[6], v[7]);
    o[2] = make_float4(v[8], v[9], v[10], v[11]);
}

extern "C" void kernel_launch(void* const* d_in, const int* in_sizes, int n_in,
                              void* d_out, int out_size, void* d_ws, size_t ws_size,
                              hipStream_t stream) {
    const float4* ev = (const float4*)d_in[0];
    unsigned int* win = (unsigned int*)d_ws;   // NPIX * 4 B = ~59 MB scratch
    float* out = (float*)d_out;

    hipMemsetAsync(win, 0, (size_t)NPIX * sizeof(unsigned int), stream);

    int nev_total = BATCH * NEV;                       // 8,000,000
    int evBlocks = (nev_total + 255) / 256;            // 31250
    e2img_events<<<evBlocks, 256, 0, stream>>>(ev, win);

    int decThreads = NPIX / 4;                         // 3,686,400
    int decBlocks = (decThreads + 255) / 256;          // 14400
    e2img_decode<<<decBlocks, 256, 0, stream>>>((const uint4*)win, (float4*)out);
}

// Round 2
// 171.255 us; speedup vs baseline: 2.1220x; 2.1220x over previous
//
#include <hip/hip_runtime.h>

// Event-to-image: B=16, N=500000 events (t,x,y,p) f32 -> (16,720,1280,3) f32.
// Last-event-wins per pixel: p==1 -> (0,255,255); p==0 -> (255,0,255);
// untouched -> (255,255,510).
//
// R2 design: counting-sort events into per-(batch,row) bins (LDS histogram +
// one global atomicAdd per block-row to reserve slots), then render each row
// with LDS atomicMax over key=((i+1)<<1)|p. Removes the 8M memory-side
// atomics that limited R1 to 26 G atomics/s (306 us).

#define WIDTH   1280
#define HEIGHT  720
#define BATCH   16
#define NEV     500000
#define NROWS   (BATCH * HEIGHT)        // 11520 row bins
#define CAP     1024                    // slots per row bin; Poisson(694), P(>1024)~1e-30
#define THREADS 256
#define EPT     32
#define EVPB    (THREADS * EPT)         // 8192 events per block
#define BPB     ((NEV + EVPB - 1) / EVPB)   // 62 blocks per batch

// ws layout: [0, NROWS*4) = gfill counters; [65536, +NROWS*CAP*4) = bins (47.2 MB)

__global__ __launch_bounds__(THREADS) void scatter_k(const float4* __restrict__ ev,
                                                     unsigned int* __restrict__ gfill,
                                                     unsigned int* __restrict__ bins) {
    __shared__ unsigned int hist[HEIGHT];
    __shared__ unsigned int base[HEIGHT];
    int batch = blockIdx.x / BPB;
    int blk   = blockIdx.x % BPB;
    int ev0   = blk * EVPB;                        // offset within batch
    int cnt   = NEV - ev0; if (cnt > EVPB) cnt = EVPB;
    const float4* bev = ev + (size_t)batch * NEV + ev0;

    for (int r = threadIdx.x; r < HEIGHT; r += THREADS) hist[r] = 0u;
    __syncthreads();

    // pass 1: row histogram (LDS atomics; ~2 lanes/bank on random rows = free)
    for (int k = 0; k < EPT; ++k) {
        int e = threadIdx.x + k * THREADS;
        if (e < cnt) {
            float4 v = bev[e];
            int yi = (int)v.z;                     // floor, y >= 0
            atomicAdd(&hist[yi], 1u);
        }
    }
    __syncthreads();

    // reserve global slots: one far atomic per (block,row)
    for (int r = threadIdx.x; r < HEIGHT; r += THREADS) {
        unsigned int h = hist[r];
        if (h) base[r] = atomicAdd(&gfill[batch * HEIGHT + r], h);
    }
    __syncthreads();
    for (int r = threadIdx.x; r < HEIGHT; r += THREADS) hist[r] = 0u;
    __syncthreads();

    // pass 2: scatter packed events (rank via LDS atomic; any permutation ok,
    // the key carries the event index so max is order-independent)
    for (int k = 0; k < EPT; ++k) {
        int e = threadIdx.x + k * THREADS;
        if (e < cnt) {
            float4 v = bev[e];
            int xi = (int)v.y;
            int yi = (int)v.z;
            unsigned int pbit = (v.w == 1.0f) ? 1u : 0u;
            unsigned int key  = (((unsigned int)(ev0 + e) + 1u) << 1) | pbit;  // 20 bits
            unsigned int pk   = ((unsigned int)xi << 20) | key;                // 11 + 20 = 31 bits
            unsigned int rank = atomicAdd(&hist[yi], 1u);
            unsigned int slot = base[yi] + rank;
            if (slot < CAP)
                bins[((size_t)(batch * HEIGHT + yi)) * CAP + slot] = pk;
        }
    }
}

__global__ __launch_bounds__(THREADS) void render_k(const unsigned int* __restrict__ gfill,
                                                    const unsigned int* __restrict__ bins,
                                                    float4* __restrict__ out) {
    __shared__ unsigned int win[WIDTH];
    int rowid = blockIdx.x;                        // batch*720 + y
    for (int x = threadIdx.x; x < WIDTH; x += THREADS) win[x] = 0u;
    __syncthreads();

    unsigned int cnt = gfill[rowid]; if (cnt > CAP) cnt = CAP;
    const unsigned int* bb = bins + (size_t)rowid * CAP;
    for (unsigned int j = threadIdx.x; j < cnt; j += THREADS) {
        unsigned int pk = bb[j];
        atomicMax(&win[pk >> 20], pk & 0xFFFFFu);  // LDS atomic
    }
    __syncthreads();

    // write one image row: 1280 px * 3 ch = 960 float4, fully coalesced
    float4* orow = out + (size_t)rowid * (WIDTH * 3 / 4);
    for (int j = threadIdx.x; j < WIDTH * 3 / 4; j += THREADS) {
        float vals[4];
#pragma unroll
        for (int c = 0; c < 4; ++c) {
            int fi = j * 4 + c;
            int px = fi / 3;                       // magic-mul div
            int ch = fi - px * 3;
            unsigned int k = win[px];
            float val;
            if (k == 0u) val = (ch == 2) ? 510.0f : 255.0f;
            else if (ch == 2) val = 255.0f;
            else if (ch == 0) val = (k & 1u) ? 0.0f : 255.0f;
            else              val = (k & 1u) ? 255.0f : 0.0f;
            vals[c] = val;
        }
        orow[j] = make_float4(vals[0], vals[1], vals[2], vals[3]);
    }
}

extern "C" void kernel_launch(void* const* d_in, const int* in_sizes, int n_in,
                              void* d_out, int out_size, void* d_ws, size_t ws_size,
                              hipStream_t stream) {
    const float4* ev = (const float4*)d_in[0];
    unsigned int* gfill = (unsigned int*)d_ws;
    unsigned int* bins  = (unsigned int*)((char*)d_ws + 65536);
    float4* out = (float4*)d_out;

    hipMemsetAsync(gfill, 0, NROWS * sizeof(unsigned int), stream);
    scatter_k<<<BATCH * BPB, THREADS, 0, stream>>>(ev, gfill, bins);
    render_k<<<NROWS, THREADS, 0, stream>>>(gfill, bins, out);
}

// Round 3
// 101.037 us; speedup vs baseline: 3.5968x; 1.6950x over previous
//
#include <hip/hip_runtime.h>

// Event-to-image: B=16, N=500000 events (t,x,y,p) f32 -> (16,720,1280,3) f32.
// Last-event-wins per pixel: p==1 -> (0,255,255); p==0 -> (255,0,255);
// untouched -> (255,255,510). Reproduced order-independently via
// max over key = ((event_idx+1)<<1)|p, packed as pk = x<<20 | key (31 bits).
//
// R3: R2's scatter wrote 8M random 4B values -> 224 MB of RMW line traffic
// (the 153us bottleneck). Now each block LDS-counting-sorts its 8192 events
// by row and writes ONE contiguous 32KB chunk (coalesced uint4) + a 721-entry
// row-prefix table. Render gathers each row's ~694 events from the 62
// per-block segments (L2/L3-resident) via prefix-scan + binary search.

#define WIDTH   1280
#define HEIGHT  720
#define BATCH   16
#define NEV     500000
#define THREADS 256
#define EPT     32
#define EVPB    (THREADS * EPT)             // 8192 events per block
#define BPB     ((NEV + EVPB - 1) / EVPB)   // 62 blocks per batch
#define NBLK    (BATCH * BPB)               // 992
#define PH      (HEIGHT + 1)                // 721 prefix entries per block

// ws layout: [0, NBLK*PH*4)=pref_g (2.86 MB); [0x400000, +NBLK*EVPB*4)=bins (32.5 MB)

__global__ __launch_bounds__(THREADS) void scatter_k(const float4* __restrict__ ev,
                                                     unsigned int* __restrict__ pref_g,
                                                     unsigned int* __restrict__ bins) {
    __shared__ unsigned int hist[HEIGHT];
    __shared__ unsigned int offs[HEIGHT];
    __shared__ unsigned int ssum[THREADS];
    __shared__ unsigned int stage[EVPB];     // 32 KB

    int t = threadIdx.x;
    int batch = blockIdx.x / BPB;
    int blk   = blockIdx.x % BPB;
    int ev0   = blk * EVPB;
    int cnt   = NEV - ev0; if (cnt > EVPB) cnt = EVPB;
    const float4* bev = ev + (size_t)batch * NEV + ev0;

    for (int r = t; r < HEIGHT; r += THREADS) hist[r] = 0u;
    __syncthreads();

    // pass 1: row histogram
    for (int k = 0; k < EPT; ++k) {
        int e = t + k * THREADS;
        if (e < cnt) {
            float4 v = bev[e];
            atomicAdd(&hist[(int)v.z], 1u);
        }
    }
    __syncthreads();

    // exclusive prefix over 720 rows: 3 rows/thread + Hillis-Steele over 256
    unsigned int own = 0;
    int b3 = t * 3;                          // 720 = 240*3
    if (b3 < HEIGHT) own = hist[b3] + hist[b3 + 1] + hist[b3 + 2];
    ssum[t] = own;
    __syncthreads();
    for (int d = 1; d < THREADS; d <<= 1) {
        unsigned int v = (t >= d) ? ssum[t - d] : 0u;
        __syncthreads();
        ssum[t] += v;
        __syncthreads();
    }
    unsigned int total = ssum[THREADS - 1];  // == cnt
    if (b3 < HEIGHT) {
        unsigned int run = ssum[t] - own;    // exclusive chunk base
        for (int k = 0; k < 3; ++k) {
            offs[b3 + k] = run;
            run += hist[b3 + k];
        }
    }
    __syncthreads();

    // publish per-block row prefix (coalesced) BEFORE pass 2 mutates offs
    unsigned int* pg = pref_g + (size_t)blockIdx.x * PH;
    for (int r = t; r < PH; r += THREADS)
        pg[r] = (r < HEIGHT) ? offs[r] : total;
    __syncthreads();

    // pass 2: place events into stage, sorted by row
    for (int k = 0; k < EPT; ++k) {
        int e = t + k * THREADS;
        if (e < cnt) {
            float4 v = bev[e];
            int xi = (int)v.y;
            int yi = (int)v.z;
            unsigned int pbit = (v.w == 1.0f) ? 1u : 0u;
            unsigned int key  = (((unsigned int)(ev0 + e) + 1u) << 1) | pbit;  // 20 bits
            unsigned int pk   = ((unsigned int)xi << 20) | key;
            unsigned int slot = atomicAdd(&offs[yi], 1u);                      // < cnt
            stage[slot] = pk;
        }
    }
    __syncthreads();

    // write the sorted chunk out, fully coalesced
    uint4* dst = (uint4*)(bins + (size_t)blockIdx.x * EVPB);
    const uint4* src = (const uint4*)stage;
    for (int k = t; k < EVPB / 4; k += THREADS)
        dst[k] = src[k];
}

__global__ __launch_bounds__(THREADS) void render_k(const unsigned int* __restrict__ pref_g,
                                                    const unsigned int* __restrict__ bins,
                                                    float4* __restrict__ out) {
    __shared__ unsigned int win[WIDTH];
    __shared__ unsigned int segbase[BPB];
    __shared__ unsigned int segpref[65];     // [0..62] used, +2 pad for lanes 62,63

    int t = threadIdx.x;
    int rowid = blockIdx.x;                  // batch*720 + y
    int batch = rowid / HEIGHT;
    int r     = rowid - batch * HEIGHT;

    for (int x = t; x < WIDTH; x += THREADS) win[x] = 0u;

    unsigned int mycnt = 0;
    if (t < BPB) {
        const unsigned int* pg = pref_g + (size_t)(batch * BPB + t) * PH + r;
        unsigned int p0 = pg[0], p1 = pg[1];
        segbase[t] = (unsigned int)((batch * BPB + t) * EVPB) + p0;
        mycnt = p1 - p0;
    }
    if (t < 64) {                            // wave-0 inclusive scan over 62 counts
        unsigned int v = mycnt;
        for (int d = 1; d < 64; d <<= 1) {
            unsigned int n = __shfl_up(v, d);
            if (t >= d) v += n;
        }
        if (t == 0) segpref[0] = 0u;
        segpref[t + 1] = v;
    }
    __syncthreads();

    unsigned int total = segpref[BPB];       // ~694
    for (unsigned int j = t; j < total; j += THREADS) {
        int lo = 0, hi = BPB - 1;            // largest s with segpref[s] <= j
        while (lo < hi) {
            int mid = (lo + hi + 1) >> 1;
            if (segpref[mid] <= j) lo = mid; else hi = mid - 1;
        }
        unsigned int pk = bins[segbase[lo] + (j - segpref[lo])];
        atomicMax(&win[pk >> 20], pk & 0xFFFFFu);
    }
    __syncthreads();

    // write one image row: 1280 px * 3 ch = 960 float4, coalesced
    float4* orow = out + (size_t)rowid * (WIDTH * 3 / 4);
    for (int j = t; j < WIDTH * 3 / 4; j += THREADS) {
        float vals[4];
#pragma unroll
        for (int c = 0; c < 4; ++c) {
            int fi = j * 4 + c;
            int px = fi / 3;
            int ch = fi - px * 3;
            unsigned int k = win[px];
            float val;
            if (k == 0u) val = (ch == 2) ? 510.0f : 255.0f;
            else if (ch == 2) val = 255.0f;
            else if (ch == 0) val = (k & 1u) ? 0.0f : 255.0f;
            else              val = (k & 1u) ? 255.0f : 0.0f;
            vals[c] = val;
        }
        orow[j] = make_float4(vals[0], vals[1], vals[2], vals[3]);
    }
}

extern "C" void kernel_launch(void* const* d_in, const int* in_sizes, int n_in,
                              void* d_out, int out_size, void* d_ws, size_t ws_size,
                              hipStream_t stream) {
    const float4* ev = (const float4*)d_in[0];
    unsigned int* pref_g = (unsigned int*)d_ws;
    unsigned int* bins   = (unsigned int*)((char*)d_ws + 0x400000);
    float4* out = (float4*)d_out;

    scatter_k<<<NBLK, THREADS, 0, stream>>>(ev, pref_g, bins);
    render_k<<<BATCH * HEIGHT, THREADS, 0, stream>>>(pref_g, bins, out);
}